// Round 10
// baseline (49.801 us; speedup 1.0000x reference)
//
#include <hip/hip_runtime.h>

#define BATCH     256
#define INPUT_DIM 4096
#define SOMA      2048
#define BRANCHES  16
#define NDEND     32768
#define SAMPLE    32

#define THREADS   1024
#define B_T       8                       // batch rows per tile (8 bf16 per b128)
#define NBT       4                       // batch tiles per block -> 32 rows/block
#define TILE_B    (INPUT_DIM * 16)        // bytes per LDS buffer = 64 KiB

typedef unsigned int u32;
typedef float f32x2 __attribute__((ext_vector_type(2)));
typedef __attribute__((address_space(1))) const u32 gu32;
typedef __attribute__((address_space(3))) u32 lu32;

__device__ __forceinline__ void async_load16(const void* g, void* l) {
    __builtin_amdgcn_global_load_lds((const gu32*)g, (lu32*)l, 16, 0, 0);
}

__device__ __forceinline__ u32 bf16rne(float f) {   // round-to-nearest-even bf16
    u32 u = __float_as_uint(f);
    return (u + 0x7FFFu + ((u >> 16) & 1u)) >> 16;
}

// ---- pack x[256][4096] f32 -> xP[32 btile][4096 i][8 bb] bf16 (LDS image) ----
#define TT 64
__global__ __launch_bounds__(256)
void pack_kernel(const float* __restrict__ x, u32* __restrict__ xP)
{
    __shared__ float ts[TT * (TT + 1)];
    const int j  = threadIdx.x;
    const int tx = j & 63;
    const int ty = j >> 6;
    const int gi = blockIdx.x * TT;
    const int gb = blockIdx.y * TT;

    #pragma unroll
    for (int r = 0; r < 16; ++r) {
        const int b = ty + 4 * r;
        ts[tx * (TT + 1) + b] = x[(size_t)(gb + b) * INPUT_DIM + gi + tx];
    }
    __syncthreads();

    #pragma unroll
    for (int rep = 0; rep < 2; ++rep) {
        const int idx   = rep * 256 + j;
        const int i_loc = idx & 63;
        const int bg    = idx >> 6;
        const float* s  = &ts[i_loc * (TT + 1) + bg * 8];
        uint4 q;
        q.x = bf16rne(s[0]) | (bf16rne(s[1]) << 16);
        q.y = bf16rne(s[2]) | (bf16rne(s[3]) << 16);
        q.z = bf16rne(s[4]) | (bf16rne(s[5]) << 16);
        q.w = bf16rne(s[6]) | (bf16rne(s[7]) << 16);
        ((uint4*)xP)[(size_t)(gb / 8 + bg) * INPUT_DIM + gi + i_loc] = q;
    }
}

// ---------------- main fused kernel ----------------
__global__ __launch_bounds__(THREADS, 4)
void dendrite_kernel(const char* __restrict__ xP,   // [32][4096][8bb] bf16
                     const int*   __restrict__ didx,
                     const float* __restrict__ sw,
                     const float* __restrict__ sb,
                     const float* __restrict__ cw,
                     const float* __restrict__ somab,
                     float* __restrict__ soma_out,   // [BATCH][SOMA]
                     float* __restrict__ dend_out)   // [BATCH][NDEND]
{
    extern __shared__ char xs[];                    // 2 x 64 KiB double buffer

    const int t  = threadIdx.x;
    const int dc = blockIdx.x;
    const int bs = blockIdx.y;
    const int d  = dc * THREADS + t;                // this thread's dendrite, forever

    // ---- idx/w/bias/cable ONCE into registers ----
    uint  off[SAMPLE / 2];
    float w[SAMPLE];
    {
        const int4*   ip = (const int4*)  (didx + (size_t)d * SAMPLE);
        const float4* wp = (const float4*)(sw   + (size_t)d * SAMPLE);
        #pragma unroll
        for (int g = 0; g < SAMPLE / 4; ++g) {
            const int4   iv = ip[g];
            const float4 wv = wp[g];
            off[2*g]   = ((u32)iv.x << 4) | ((u32)iv.y << 20);  // byte off = i*16
            off[2*g+1] = ((u32)iv.z << 4) | ((u32)iv.w << 20);
            w[4*g] = wv.x; w[4*g+1] = wv.y; w[4*g+2] = wv.z; w[4*g+3] = wv.w;
        }
    }
    const float bias = sb[d];
    const float cwv  = cw[d];
    const int   n    = d >> 4;
    const float sbi  = somab[n];

    // ---- prologue: async stage tile 0 into buffer 0 (zero VGPR) ----
    {
        const char* tb = xP + (size_t)(bs * NBT) * TILE_B;
        #pragma unroll
        for (int r = 0; r < TILE_B / 16 / THREADS; ++r) {   // 4 per thread
            const int o = (r * THREADS + t) * 16;
            async_load16(tb + o, xs + o);
        }
    }

    float a_prev[B_T];                              // deferred raw accumulators
    #pragma unroll
    for (int bb = 0; bb < B_T; ++bb) a_prev[bb] = 0.f;

    for (int k = 0; k < NBT; ++k) {
        const int b0 = bs * (B_T * NBT) + k * B_T;

        // implicit s_waitcnt vmcnt(0) lgkmcnt(0) + barrier:
        //  - stage(k) has landed; buffer (k+1)&1 readers (tile k-1) are done
        //  - stores issued after the PREVIOUS barrier had a full tile to drain
        __syncthreads();

        // ---- deferred epilogue for tile k-1: stores issued right after the
        //      barrier -> full stage+gather gap before the next vmcnt(0) ----
        if (k > 0) {
            const int pb0 = b0 - B_T;
            float part[B_T];
            #pragma unroll
            for (int bb = 0; bb < B_T; ++bb) {
                const float pre = a_prev[bb] + bias;
                const float act = (pre >= 0.f) ? pre : 0.1f * pre;
                dend_out[(size_t)(pb0 + bb) * NDEND + d] = act;   // coalesced
                part[bb] = act * cwv;
            }
            #pragma unroll
            for (int m = 1; m < BRANCHES; m <<= 1) {
                #pragma unroll
                for (int bb = 0; bb < B_T; ++bb)
                    part[bb] += __shfl_xor(part[bb], m);
            }
            if ((t & (BRANCHES - 1)) == 0) {
                #pragma unroll
                for (int bb = 0; bb < B_T; ++bb) {
                    const float pre = part[bb] + sbi;
                    soma_out[(size_t)(pb0 + bb) * SOMA + n] =
                        (pre >= 0.f) ? pre : 0.1f * pre;
                }
            }
        }

        if (k + 1 < NBT) {                          // async stage(k+1), other buffer
            const char* tb = xP + (size_t)(bs * NBT + k + 1) * TILE_B;
            char* nbuf = xs + ((k + 1) & 1) * TILE_B;
            #pragma unroll
            for (int r = 0; r < TILE_B / 16 / THREADS; ++r) {
                const int o = (r * THREADS + t) * 16;
                async_load16(tb + o, nbuf + o);
            }
        }

        // ---- gather + unpack + packed FMA (regs + LDS only) ----
        const char* buf = xs + (k & 1) * TILE_B;
        f32x2 acc0 = {0.f,0.f}, acc1 = {0.f,0.f}, acc2 = {0.f,0.f}, acc3 = {0.f,0.f};
        #pragma unroll
        for (int g = 0; g < SAMPLE / 2; ++g) {
            const u32 pr = off[g];
            const uint4 q0 = *(const uint4*)(buf + (pr & 0xFFFFu));
            const uint4 q1 = *(const uint4*)(buf + (pr >> 16));
            const f32x2 w0 = {w[2*g],   w[2*g]};
            const f32x2 w1 = {w[2*g+1], w[2*g+1]};
            f32x2 v;
            v = (f32x2){__uint_as_float(q0.x << 16), __uint_as_float(q0.x & 0xFFFF0000u)};
            acc0 += v * w0;
            v = (f32x2){__uint_as_float(q0.y << 16), __uint_as_float(q0.y & 0xFFFF0000u)};
            acc1 += v * w0;
            v = (f32x2){__uint_as_float(q0.z << 16), __uint_as_float(q0.z & 0xFFFF0000u)};
            acc2 += v * w0;
            v = (f32x2){__uint_as_float(q0.w << 16), __uint_as_float(q0.w & 0xFFFF0000u)};
            acc3 += v * w0;
            v = (f32x2){__uint_as_float(q1.x << 16), __uint_as_float(q1.x & 0xFFFF0000u)};
            acc0 += v * w1;
            v = (f32x2){__uint_as_float(q1.y << 16), __uint_as_float(q1.y & 0xFFFF0000u)};
            acc1 += v * w1;
            v = (f32x2){__uint_as_float(q1.z << 16), __uint_as_float(q1.z & 0xFFFF0000u)};
            acc2 += v * w1;
            v = (f32x2){__uint_as_float(q1.w << 16), __uint_as_float(q1.w & 0xFFFF0000u)};
            acc3 += v * w1;
        }
        a_prev[0] = acc0.x; a_prev[1] = acc0.y;
        a_prev[2] = acc1.x; a_prev[3] = acc1.y;
        a_prev[4] = acc2.x; a_prev[5] = acc2.y;
        a_prev[6] = acc3.x; a_prev[7] = acc3.y;
    }

    // ---- final epilogue (tile NBT-1) ----
    {
        const int pb0 = bs * (B_T * NBT) + (NBT - 1) * B_T;
        float part[B_T];
        #pragma unroll
        for (int bb = 0; bb < B_T; ++bb) {
            const float pre = a_prev[bb] + bias;
            const float act = (pre >= 0.f) ? pre : 0.1f * pre;
            dend_out[(size_t)(pb0 + bb) * NDEND + d] = act;
            part[bb] = act * cwv;
        }
        #pragma unroll
        for (int m = 1; m < BRANCHES; m <<= 1) {
            #pragma unroll
            for (int bb = 0; bb < B_T; ++bb)
                part[bb] += __shfl_xor(part[bb], m);
        }
        if ((t & (BRANCHES - 1)) == 0) {
            #pragma unroll
            for (int bb = 0; bb < B_T; ++bb) {
                const float pre = part[bb] + sbi;
                soma_out[(size_t)(pb0 + bb) * SOMA + n] =
                    (pre >= 0.f) ? pre : 0.1f * pre;
            }
        }
    }
}

extern "C" void kernel_launch(void* const* d_in, const int* in_sizes, int n_in,
                              void* d_out, int out_size, void* d_ws, size_t ws_size,
                              hipStream_t stream) {
    const float* x     = (const float*)d_in[0];
    const int*   didx  = (const int*)  d_in[1];
    const float* sw    = (const float*)d_in[2];
    const float* sb    = (const float*)d_in[3];
    const float* cw    = (const float*)d_in[4];
    const float* somab = (const float*)d_in[5];

    float* soma_out = (float*)d_out;                     // [256][2048]
    float* dend_out = soma_out + (size_t)BATCH * SOMA;   // [256][32768]
    u32*   xP       = (u32*)d_ws;                        // 2 MiB bf16 LDS image

    static bool attr_set = false;                        // idempotent host config
    if (!attr_set) {
        hipFuncSetAttribute((const void*)dendrite_kernel,
                            hipFuncAttributeMaxDynamicSharedMemorySize, 2 * TILE_B);
        attr_set = true;
    }

    dim3 pgrid(INPUT_DIM / TT, BATCH / TT);              // (64, 4)
    pack_kernel<<<pgrid, 256, 0, stream>>>(x, xP);

    dim3 grid(NDEND / THREADS, BATCH / (B_T * NBT));     // (32, 8) = 256 blocks, 1/CU
    dendrite_kernel<<<grid, THREADS, 2 * TILE_B, stream>>>(
        (const char*)xP, didx, sw, sb, cw, somab, soma_out, dend_out);
}

// Round 11
// 46.438 us; speedup vs baseline: 1.0724x; 1.0724x over previous
//
#include <hip/hip_runtime.h>

#define BATCH     256
#define INPUT_DIM 4096
#define SOMA      2048
#define BRANCHES  16
#define NDEND     32768
#define SAMPLE    32

#define THREADS   1024
#define B_T       8                       // batch rows per tile (8 bf16 per b128)
#define NBT       4                       // batch tiles per block -> 32 rows/block
#define TILE_B    (INPUT_DIM * 16)        // bytes per LDS buffer = 64 KiB

typedef unsigned int u32;
typedef float f32x2 __attribute__((ext_vector_type(2)));
typedef __attribute__((address_space(1))) const u32 gu32;
typedef __attribute__((address_space(3))) u32 lu32;

__device__ __forceinline__ void async_load16(const void* g, void* l) {
    __builtin_amdgcn_global_load_lds((const gu32*)g, (lu32*)l, 16, 0, 0);
}

__device__ __forceinline__ u32 bf16rne(float f) {   // round-to-nearest-even bf16
    u32 u = __float_as_uint(f);
    return (u + 0x7FFFu + ((u >> 16) & 1u)) >> 16;
}

// 16-lane sum via DPP (VALU pipe only — no LDS): xor1, xor2, half_mirror, mirror.
// All hops stay inside 16-lane rows; our 16-lane groups are 16-aligned.
__device__ __forceinline__ float dpp_red16(float v) {
    int x;
    x = __builtin_amdgcn_update_dpp(0, __float_as_int(v), 0xB1,  0xF, 0xF, true);
    v += __int_as_float(x);                         // quad_perm [1,0,3,2] = xor1
    x = __builtin_amdgcn_update_dpp(0, __float_as_int(v), 0x4E,  0xF, 0xF, true);
    v += __int_as_float(x);                         // quad_perm [2,3,0,1] = xor2
    x = __builtin_amdgcn_update_dpp(0, __float_as_int(v), 0x141, 0xF, 0xF, true);
    v += __int_as_float(x);                         // row_half_mirror (xor4-equiv)
    x = __builtin_amdgcn_update_dpp(0, __float_as_int(v), 0x140, 0xF, 0xF, true);
    v += __int_as_float(x);                         // row_mirror (xor8-equiv)
    return v;
}

// ---- pack x[256][4096] f32 -> xP[32 btile][4096 i][8 bb] bf16 (LDS image) ----
#define TT 64
__global__ __launch_bounds__(256)
void pack_kernel(const float* __restrict__ x, u32* __restrict__ xP)
{
    __shared__ float ts[TT * (TT + 1)];
    const int j  = threadIdx.x;
    const int tx = j & 63;
    const int ty = j >> 6;
    const int gi = blockIdx.x * TT;
    const int gb = blockIdx.y * TT;

    #pragma unroll
    for (int r = 0; r < 16; ++r) {
        const int b = ty + 4 * r;
        ts[tx * (TT + 1) + b] = x[(size_t)(gb + b) * INPUT_DIM + gi + tx];
    }
    __syncthreads();

    #pragma unroll
    for (int rep = 0; rep < 2; ++rep) {
        const int idx   = rep * 256 + j;
        const int i_loc = idx & 63;
        const int bg    = idx >> 6;
        const float* s  = &ts[i_loc * (TT + 1) + bg * 8];
        uint4 q;
        q.x = bf16rne(s[0]) | (bf16rne(s[1]) << 16);
        q.y = bf16rne(s[2]) | (bf16rne(s[3]) << 16);
        q.z = bf16rne(s[4]) | (bf16rne(s[5]) << 16);
        q.w = bf16rne(s[6]) | (bf16rne(s[7]) << 16);
        ((uint4*)xP)[(size_t)(gb / 8 + bg) * INPUT_DIM + gi + i_loc] = q;
    }
}

// ---------------- main fused kernel ----------------
__global__ __launch_bounds__(THREADS, 4)
void dendrite_kernel(const char* __restrict__ xP,   // [32][4096][8bb] bf16
                     const int*   __restrict__ didx,
                     const float* __restrict__ sw,
                     const float* __restrict__ sb,
                     const float* __restrict__ cw,
                     const float* __restrict__ somab,
                     float* __restrict__ soma_out,   // [BATCH][SOMA]
                     float* __restrict__ dend_out)   // [BATCH][NDEND]
{
    extern __shared__ char xs[];                    // 2 x 64 KiB double buffer

    const int t  = threadIdx.x;
    const int dc = blockIdx.x;
    const int bs = blockIdx.y;
    const int d  = dc * THREADS + t;                // this thread's dendrite, forever

    // ---- idx/w/bias/cable ONCE into registers ----
    uint  off[SAMPLE / 2];
    float w[SAMPLE];
    {
        const int4*   ip = (const int4*)  (didx + (size_t)d * SAMPLE);
        const float4* wp = (const float4*)(sw   + (size_t)d * SAMPLE);
        #pragma unroll
        for (int g = 0; g < SAMPLE / 4; ++g) {
            const int4   iv = ip[g];
            const float4 wv = wp[g];
            off[2*g]   = ((u32)iv.x << 4) | ((u32)iv.y << 20);  // byte off = i*16
            off[2*g+1] = ((u32)iv.z << 4) | ((u32)iv.w << 20);
            w[4*g] = wv.x; w[4*g+1] = wv.y; w[4*g+2] = wv.z; w[4*g+3] = wv.w;
        }
    }
    const float bias = sb[d];
    const float cwv  = cw[d];
    const int   n    = d >> 4;
    const float sbi  = somab[n];

    // ---- prologue: async stage tile 0 into buffer 0 (zero VGPR) ----
    {
        const char* tb = xP + (size_t)(bs * NBT) * TILE_B;
        #pragma unroll
        for (int r = 0; r < TILE_B / 16 / THREADS; ++r) {   // 4 per thread
            const int o = (r * THREADS + t) * 16;
            async_load16(tb + o, xs + o);
        }
    }

    float a_prev[B_T];                              // deferred raw accumulators
    #pragma unroll
    for (int bb = 0; bb < B_T; ++bb) a_prev[bb] = 0.f;

    for (int k = 0; k < NBT; ++k) {
        const int b0 = bs * (B_T * NBT) + k * B_T;

        // implicit s_waitcnt vmcnt(0) lgkmcnt(0) + barrier:
        //  - stage(k) landed; buffer (k+1)&1 readers (tile k-1) done
        //  - tile k-1's nt stores had the whole gather(k-1) to drain
        __syncthreads();

        if (k + 1 < NBT) {                          // async stage(k+1) first: max window
            const char* tb = xP + (size_t)(bs * NBT + k + 1) * TILE_B;
            char* nbuf = xs + ((k + 1) & 1) * TILE_B;
            #pragma unroll
            for (int r = 0; r < TILE_B / 16 / THREADS; ++r) {
                const int o = (r * THREADS + t) * 16;
                async_load16(tb + o, nbuf + o);
            }
        }

        // ---- deferred epilogue for tile k-1 (nt stores drain under gather k) ----
        if (k > 0) {
            const int pb0 = b0 - B_T;
            #pragma unroll
            for (int bb = 0; bb < B_T; ++bb) {
                const float pre = a_prev[bb] + bias;
                const float act = (pre >= 0.f) ? pre : 0.1f * pre;
                __builtin_nontemporal_store(act,
                    &dend_out[(size_t)(pb0 + bb) * NDEND + d]);      // coalesced
                const float s16 = dpp_red16(act * cwv);              // VALU-only reduce
                if ((t & (BRANCHES - 1)) == 0) {
                    const float pre2 = s16 + sbi;
                    soma_out[(size_t)(pb0 + bb) * SOMA + n] =
                        (pre2 >= 0.f) ? pre2 : 0.1f * pre2;
                }
            }
        }

        // ---- gather + unpack + packed FMA (regs + LDS only) ----
        const char* buf = xs + (k & 1) * TILE_B;
        f32x2 acc0 = {0.f,0.f}, acc1 = {0.f,0.f}, acc2 = {0.f,0.f}, acc3 = {0.f,0.f};
        #pragma unroll
        for (int g = 0; g < SAMPLE / 2; ++g) {
            const u32 pr = off[g];
            const uint4 q0 = *(const uint4*)(buf + (pr & 0xFFFFu));
            const uint4 q1 = *(const uint4*)(buf + (pr >> 16));
            const f32x2 w0 = {w[2*g],   w[2*g]};
            const f32x2 w1 = {w[2*g+1], w[2*g+1]};
            f32x2 v;
            v = (f32x2){__uint_as_float(q0.x << 16), __uint_as_float(q0.x & 0xFFFF0000u)};
            acc0 += v * w0;
            v = (f32x2){__uint_as_float(q0.y << 16), __uint_as_float(q0.y & 0xFFFF0000u)};
            acc1 += v * w0;
            v = (f32x2){__uint_as_float(q0.z << 16), __uint_as_float(q0.z & 0xFFFF0000u)};
            acc2 += v * w0;
            v = (f32x2){__uint_as_float(q0.w << 16), __uint_as_float(q0.w & 0xFFFF0000u)};
            acc3 += v * w0;
            v = (f32x2){__uint_as_float(q1.x << 16), __uint_as_float(q1.x & 0xFFFF0000u)};
            acc0 += v * w1;
            v = (f32x2){__uint_as_float(q1.y << 16), __uint_as_float(q1.y & 0xFFFF0000u)};
            acc1 += v * w1;
            v = (f32x2){__uint_as_float(q1.z << 16), __uint_as_float(q1.z & 0xFFFF0000u)};
            acc2 += v * w1;
            v = (f32x2){__uint_as_float(q1.w << 16), __uint_as_float(q1.w & 0xFFFF0000u)};
            acc3 += v * w1;
        }
        a_prev[0] = acc0.x; a_prev[1] = acc0.y;
        a_prev[2] = acc1.x; a_prev[3] = acc1.y;
        a_prev[4] = acc2.x; a_prev[5] = acc2.y;
        a_prev[6] = acc3.x; a_prev[7] = acc3.y;
    }

    // ---- final epilogue (tile NBT-1) ----
    {
        const int pb0 = bs * (B_T * NBT) + (NBT - 1) * B_T;
        #pragma unroll
        for (int bb = 0; bb < B_T; ++bb) {
            const float pre = a_prev[bb] + bias;
            const float act = (pre >= 0.f) ? pre : 0.1f * pre;
            __builtin_nontemporal_store(act,
                &dend_out[(size_t)(pb0 + bb) * NDEND + d]);
            const float s16 = dpp_red16(act * cwv);
            if ((t & (BRANCHES - 1)) == 0) {
                const float pre2 = s16 + sbi;
                soma_out[(size_t)(pb0 + bb) * SOMA + n] =
                    (pre2 >= 0.f) ? pre2 : 0.1f * pre2;
            }
        }
    }
}

extern "C" void kernel_launch(void* const* d_in, const int* in_sizes, int n_in,
                              void* d_out, int out_size, void* d_ws, size_t ws_size,
                              hipStream_t stream) {
    const float* x     = (const float*)d_in[0];
    const int*   didx  = (const int*)  d_in[1];
    const float* sw    = (const float*)d_in[2];
    const float* sb    = (const float*)d_in[3];
    const float* cw    = (const float*)d_in[4];
    const float* somab = (const float*)d_in[5];

    float* soma_out = (float*)d_out;                     // [256][2048]
    float* dend_out = soma_out + (size_t)BATCH * SOMA;   // [256][32768]
    u32*   xP       = (u32*)d_ws;                        // 2 MiB bf16 LDS image

    static bool attr_set = false;                        // idempotent host config
    if (!attr_set) {
        hipFuncSetAttribute((const void*)dendrite_kernel,
                            hipFuncAttributeMaxDynamicSharedMemorySize, 2 * TILE_B);
        attr_set = true;
    }

    dim3 pgrid(INPUT_DIM / TT, BATCH / TT);              // (64, 4)
    pack_kernel<<<pgrid, 256, 0, stream>>>(x, xP);

    dim3 grid(NDEND / THREADS, BATCH / (B_T * NBT));     // (32, 8) = 256 blocks, 1/CU
    dendrite_kernel<<<grid, THREADS, 2 * TILE_B, stream>>>(
        (const char*)xP, didx, sw, sb, cw, somab, soma_out, dend_out);
}